// Round 6
// baseline (2111.035 us; speedup 1.0000x reference)
//
#include <hip/hip_runtime.h>
#include <hip/hip_cooperative_groups.h>
#include <cstdint>
#include <cstddef>

namespace cg = cooperative_groups;

// HiPPO x_{k+1} = Ab x_k + b u_k, f[k]=x_{k+1}, L=65536, N=512.
// Chunked scan (C=16, G=4096): one big GEMM F(4096x8192)=Xcat(4096x544)@Wcat,
// chunk states via Blelloch sweep with on-device matrix powers.
// Numerics: split-f16 (Ootomo), fp32 accumulate -> ~22-bit mantissa.
// R10: R8/R9 NaN root-caused to an inlining bug in chain_kernel's l=0 phase:
// M must be 2048 (odd-row count), not 4096 -- the overflow blocks wrote Xch
// rows 4096..8191 which alias the Xcl overlay (low-split corruption -> NaN).
// Fixed (vb<256, M=2048). Coop mega-kernel (30 grid.syncs) + checked launch
// + proven R3 fallback retained unchanged. gemm_main unchanged (113us).
// Workspace ~46 MB (stay under 53 MB).

typedef _Float16 half_t;
typedef _Float16 f16x8 __attribute__((ext_vector_type(8)));
typedef float f32x4 __attribute__((ext_vector_type(4)));

static constexpr int KPAD = 544;               // 512 + 16 u-taps + 16 pad
static constexpr size_t MSZ = (size_t)512 * 512;
static constexpr float INV2048 = 1.f / 2048.f;

__device__ inline void split1(float v, half_t& h, half_t& l) {
  h = (half_t)v;
  l = (half_t)((v - (float)h) * 2048.f);
}
// residual split: l is the true residual (no 2048 scale); consumer (gemm_main)
// accumulates h*l' + l*h' directly into the same fp32 accumulator.
__device__ inline void split1r(float v, half_t& h, half_t& l) {
  h = (half_t)v;
  l = (half_t)(v - (float)h);
}

// -------- chain GEMM body: C += A(512x512 fp32) @ B(512x512 fp32) ------------
// split-on-the-fly, fragment-native LDS, one split-K=4 slice (sl), 64x64 tile.
// Depth-2 register prefetch: global loads for kt+1 issue under kt's mfma.
__device__ __forceinline__ void sq_body(
    const float* __restrict__ A, const float* __restrict__ B, float* __restrict__ C,
    int bx, int by, int sl,
    half_t* __restrict__ Ash, half_t* __restrict__ Asl,
    half_t* __restrict__ Bsh, half_t* __restrict__ Bsl) {
  int m0 = bx * 64, n0 = by * 64;
  int tid = threadIdx.x, wave = tid >> 6, lane = tid & 63;
  int wm = (wave & 1) * 32, wn = (wave >> 1) * 32;
  f32x4 acc[2][2], accc[2][2];
#pragma unroll
  for (int i = 0; i < 2; ++i)
#pragma unroll
    for (int j = 0; j < 2; ++j) {
      acc[i][j] = (f32x4){0.f, 0.f, 0.f, 0.f};
      accc[i][j] = (f32x4){0.f, 0.f, 0.f, 0.f};
    }
  int rb = tid >> 6, mm = tid & 15, kseg = (tid >> 4) & 3;
  const float* ar = A + (size_t)(m0 + rb * 16 + mm) * 512 + sl * 128 + kseg * 8;
  const float* bc = B + (size_t)(sl * 128 + kseg * 8) * 512 + n0 + rb * 16 + mm;
  float4 a0 = *(const float4*)ar, a1 = *(const float4*)(ar + 4);
  float bv[8];
#pragma unroll
  for (int j = 0; j < 8; ++j) bv[j] = bc[(size_t)j * 512];
#pragma unroll
  for (int kt = 0; kt < 4; ++kt) {
    {
      float aa[8] = {a0.x, a0.y, a0.z, a0.w, a1.x, a1.y, a1.z, a1.w};
      f16x8 hv, lv;
#pragma unroll
      for (int j = 0; j < 8; ++j) { half_t h, l; split1(aa[j], h, l); hv[j] = h; lv[j] = l; }
      *(f16x8*)(Ash + tid * 8) = hv;
      *(f16x8*)(Asl + tid * 8) = lv;
#pragma unroll
      for (int j = 0; j < 8; ++j) { half_t h, l; split1(bv[j], h, l); hv[j] = h; lv[j] = l; }
      *(f16x8*)(Bsh + tid * 8) = hv;
      *(f16x8*)(Bsl + tid * 8) = lv;
    }
    __syncthreads();
    if (kt < 3) {   // prefetch kt+1 under this kt's ds_read+mfma
      a0 = *(const float4*)(ar + (kt + 1) * 32);
      a1 = *(const float4*)(ar + (kt + 1) * 32 + 4);
#pragma unroll
      for (int j = 0; j < 8; ++j) bv[j] = bc[(size_t)((kt + 1) * 32 + j) * 512];
    }
    f16x8 afh[2], afl[2], bfh[2], bfl[2];
#pragma unroll
    for (int i = 0; i < 2; ++i) {
      int ra = (wm >> 4) + i, rbn = (wn >> 4) + i;
      afh[i] = *(const f16x8*)(Ash + ra * 512 + lane * 8);
      afl[i] = *(const f16x8*)(Asl + ra * 512 + lane * 8);
      bfh[i] = *(const f16x8*)(Bsh + rbn * 512 + lane * 8);
      bfl[i] = *(const f16x8*)(Bsl + rbn * 512 + lane * 8);
    }
#pragma unroll
    for (int i = 0; i < 2; ++i)
#pragma unroll
      for (int j = 0; j < 2; ++j) {
        acc[i][j] = __builtin_amdgcn_mfma_f32_16x16x32_f16(afh[i], bfh[j], acc[i][j], 0, 0, 0);
        accc[i][j] = __builtin_amdgcn_mfma_f32_16x16x32_f16(afh[i], bfl[j], accc[i][j], 0, 0, 0);
        accc[i][j] = __builtin_amdgcn_mfma_f32_16x16x32_f16(afl[i], bfh[j], accc[i][j], 0, 0, 0);
      }
    __syncthreads();
  }
  int ml = lane & 15, quad = lane >> 4;
  for (int i = 0; i < 2; ++i)
    for (int j = 0; j < 2; ++j)
      for (int rr = 0; rr < 4; ++rr) {
        int gm = m0 + wm + i * 16 + quad * 4 + rr;
        int gn = n0 + wn + j * 16 + ml;
        atomicAdd(&C[(size_t)gm * 512 + gn], acc[i][j][rr] + accc[i][j][rr] * INV2048);
      }
}

// -------- sweep GEMM body: C(Mx512) = A(Mx512 f16) @ S^T + D; S fp32 ---------
// Depth-2 register prefetch; fused even-row copy (down-sweep rowcopy).
__device__ __forceinline__ void sweep_body(
    const half_t* __restrict__ A, long ldA, const float* __restrict__ BT,
    const half_t* __restrict__ D, long ldD,
    half_t* __restrict__ Ch, half_t* __restrict__ Cl, long ldC,
    int rScale, int rOff, int doCopy, int M, int bx, int by,
    half_t* __restrict__ Ash, half_t* __restrict__ Bsh, half_t* __restrict__ Bsl) {
  int m0 = bx * 64, n0 = by * 64;
  int tid = threadIdx.x, wave = tid >> 6, lane = tid & 63;
  int wm = (wave & 1) * 32, wn = (wave >> 1) * 32;
  f32x4 acc[2][2], accc[2][2];
#pragma unroll
  for (int i = 0; i < 2; ++i)
#pragma unroll
    for (int j = 0; j < 2; ++j) {
      acc[i][j] = (f32x4){0.f, 0.f, 0.f, 0.f};
      accc[i][j] = (f32x4){0.f, 0.f, 0.f, 0.f};
    }
  int rb = tid >> 6, mm = tid & 15, kseg = (tid >> 4) & 3;
  int arow = m0 + rb * 16 + mm;
  const half_t* ap = A + (size_t)arow * ldA + kseg * 8;
  const float* bp = BT + (size_t)(n0 + rb * 16 + mm) * 512 + kseg * 8;
  f16x8 av = (f16x8){0, 0, 0, 0, 0, 0, 0, 0};
  if (arow < M) av = *(const f16x8*)ap;
  float4 bv0 = *(const float4*)bp;
  float4 bv1 = *(const float4*)(bp + 4);
#pragma unroll
  for (int kt = 0; kt < 16; ++kt) {
    int k0 = kt * 32;
    *(f16x8*)(Ash + tid * 8) = av;
    // fused even-row copy: out[2*arow, k0+kseg*8 ..] = A values (down-sweep)
    if (doCopy && k0 >= n0 && k0 < n0 + 64 && arow < M) {
      size_t co = (size_t)(2 * arow) * ldC + k0 + kseg * 8;
      *(f16x8*)(Ch + co) = av;
      if (Cl) *(f16x8*)(Cl + co) = (f16x8){0, 0, 0, 0, 0, 0, 0, 0};
    }
    {
      float bb[8] = {bv0.x, bv0.y, bv0.z, bv0.w, bv1.x, bv1.y, bv1.z, bv1.w};
      f16x8 hv, lv;
#pragma unroll
      for (int j = 0; j < 8; ++j) { half_t h, l; split1(bb[j], h, l); hv[j] = h; lv[j] = l; }
      *(f16x8*)(Bsh + tid * 8) = hv;
      *(f16x8*)(Bsl + tid * 8) = lv;
    }
    __syncthreads();
    if (kt < 15) {  // prefetch kt+1 under this kt's ds_read+mfma
      if (arow < M) av = *(const f16x8*)(ap + (kt + 1) * 32);
      bv0 = *(const float4*)(bp + (kt + 1) * 32);
      bv1 = *(const float4*)(bp + (kt + 1) * 32 + 4);
    }
    f16x8 af[2], bfh[2], bfl[2];
#pragma unroll
    for (int i = 0; i < 2; ++i) {
      af[i] = *(const f16x8*)(Ash + ((wm >> 4) + i) * 512 + lane * 8);
      bfh[i] = *(const f16x8*)(Bsh + ((wn >> 4) + i) * 512 + lane * 8);
      bfl[i] = *(const f16x8*)(Bsl + ((wn >> 4) + i) * 512 + lane * 8);
    }
#pragma unroll
    for (int i = 0; i < 2; ++i)
#pragma unroll
      for (int j = 0; j < 2; ++j) {
        acc[i][j] = __builtin_amdgcn_mfma_f32_16x16x32_f16(af[i], bfh[j], acc[i][j], 0, 0, 0);
        accc[i][j] = __builtin_amdgcn_mfma_f32_16x16x32_f16(af[i], bfl[j], accc[i][j], 0, 0, 0);
      }
    __syncthreads();
  }
  int ml = lane & 15, quad = lane >> 4;
  for (int i = 0; i < 2; ++i)
    for (int j = 0; j < 2; ++j)
      for (int rr = 0; rr < 4; ++rr) {
        int gm = m0 + wm + i * 16 + quad * 4 + rr;
        int gn = n0 + wn + j * 16 + ml;
        if (gm >= M) continue;
        float v = acc[i][j][rr] + accc[i][j][rr] * INV2048;
        if (D) v += (float)D[(size_t)gm * ldD + gn];
        size_t co = ((size_t)gm * rScale + rOff) * ldC + gn;
        if (Cl) { half_t h, l; split1r(v, h, l); Ch[co] = h; Cl[co] = l; }
        else Ch[co] = (half_t)v;
      }
}

// closed forms for overlay offsets (elements):
// zoff[l] = 2^22 - 2^(22-l); xoff[l] = 2^21 - 2^(22-l)
__device__ __forceinline__ size_t zoff_f(int l) {
  return ((size_t)1 << 22) - ((size_t)1 << (22 - l));
}
__device__ __forceinline__ size_t xoff_f(int l) {
  return ((size_t)1 << 21) - ((size_t)1 << (22 - l));
}

// -------- cooperative mega-kernel: entire pre-GEMM chain ---------------------
// Grid-size-agnostic (works for any G); launched with G=256 (1 block/CU).
__global__ __launch_bounds__(256, 2)
void chain_kernel(const float* __restrict__ u, const float* __restrict__ Ab,
                  const float* __restrict__ Bb, const float* __restrict__ x0,
                  float* __restrict__ Vp, float* __restrict__ Sp,
                  float* __restrict__ Kb, half_t* __restrict__ Wh,
                  half_t* __restrict__ Wl, half_t* __restrict__ x0h,
                  half_t* __restrict__ Zh, half_t* __restrict__ Xph,
                  half_t* __restrict__ Xch, half_t* __restrict__ Xcl) {
  cg::grid_group grid = cg::this_grid();
  __shared__ __align__(16) half_t s0[64 * 32], s1[64 * 32], s2[64 * 32], s3[64 * 32];
  const int bid = blockIdx.x, tid = threadIdx.x;
  const int G = gridDim.x;
  auto gsync = [&]() { __threadfence(); grid.sync(); };

  // ---- phase 0: zero V[1..15]+Sp (26*MSZ, atomic targets); copy Ab; cast x0
  {
    float4* zp = (float4*)(Vp + MSZ);
    const int n4 = (int)(26 * MSZ / 4);
    for (int i = bid * 256 + tid; i < n4; i += G * 256)
      zp[i] = make_float4(0.f, 0.f, 0.f, 0.f);
    for (int i = bid * 256 + tid; i < (int)MSZ; i += G * 256) Vp[i] = Ab[i];
    if (bid == 0) { x0h[tid] = (half_t)x0[tid]; x0h[tid + 256] = (half_t)x0[tid + 256]; }
  }
  gsync();

  // ---- V-chain by doubling: V_{t+s} = V_t @ V_s, t=1..s; s=1,2,4,8 ----
  for (int s = 1; s <= 8; s <<= 1) {
    for (int vb = bid; vb < 256 * s; vb += G) {
      int bx = vb & 7, by = (vb >> 3) & 7, z = vb >> 6, bb = z >> 2, sl = z & 3;
      sq_body(Vp + (size_t)bb * MSZ, Vp + (size_t)(s - 1) * MSZ,
              Vp + (size_t)(s + bb) * MSZ, bx, by, sl, s0, s1, s2, s3);
    }
    gsync();
  }

  // ---- kbuild: K[t,n] = (Ab^t b)[n], one wave per (t,n) ----
  {
    int wv = tid >> 6, lane = tid & 63;
    for (int gw = bid * 4 + wv; gw < 8192; gw += G * 4) {
      int t = gw >> 9, n = gw & 511;
      if (t == 0) { if (lane == 0) Kb[n] = Bb[n]; continue; }
      const float* row = Vp + (size_t)(t - 1) * MSZ + (size_t)n * 512;
      float acc = 0.f;
#pragma unroll
      for (int m = 0; m < 512; m += 64) acc += row[m + lane] * Bb[m + lane];
#pragma unroll
      for (int sft = 32; sft; sft >>= 1) acc += __shfl_down(acc, sft, 64);
      if (lane == 0) Kb[t * 512 + n] = acc;
    }
  }
  gsync();

  // ---- wcat (vectorized, 8 cols per thread-unit) ----
  {
    for (int un = bid * 256 + tid; un < 8192 * 68; un += G * 256) {
      int row = un / 68, kb = un - row * 68;
      int i = row >> 9, n = row & 511;
      f16x8 hv, lv;
      if (kb < 64) {
        const float* vp = Vp + (size_t)i * MSZ + (size_t)n * 512 + kb * 8;
        float4 v0 = *(const float4*)vp, v1 = *(const float4*)(vp + 4);
        float vv[8] = {v0.x, v0.y, v0.z, v0.w, v1.x, v1.y, v1.z, v1.w};
#pragma unroll
        for (int j = 0; j < 8; ++j) { half_t h, l; split1r(vv[j], h, l); hv[j] = h; lv[j] = l; }
      } else {
#pragma unroll
        for (int j = 0; j < 8; ++j) {
          int k = kb * 8 + j;
          float v = 0.f;
          if (k < 528) { int jj = k - 512; if (jj <= i) v = Kb[(i - jj) * 512 + n]; }
          half_t h, l; split1r(v, h, l); hv[j] = h; lv[j] = l;
        }
      }
      size_t o = (size_t)row * KPAD + kb * 8;
      *(f16x8*)(Wh + o) = hv;
      *(f16x8*)(Wl + o) = lv;
    }
  }
  gsync();   // Zh (leaf out) overlays Vp which wcat reads -> must separate

  // ---- leaf: Z0[c,n] = sum_j K[15-j,n]*u[16c+j] ----
  {
    for (int e = bid * 256 + tid; e < 4096 * 512; e += G * 256) {
      int c = e >> 9, n = e & 511;
      float acc = 0.f;
#pragma unroll
      for (int j = 0; j < 16; ++j) acc += Kb[(15 - j) * 512 + n] * u[c * 16 + j];
      Zh[(size_t)e] = (half_t)acc;
    }
  }
  gsync();

  // ---- fused up phases l=1..11: squaring T_l = T_{l-1}^2 + up-sweep l-1 ----
  for (int l = 1; l <= 11; ++l) {
    const float* T = (l == 1) ? Vp + 15 * MSZ : Sp + (size_t)(l - 2) * MSZ;
    float* Tout = Sp + (size_t)(l - 1) * MSZ;
    int Mup = 1 << (12 - l);
    int ntot = 256 + ((Mup + 63) / 64) * 8;
    const half_t* Zin = Zh + zoff_f(l - 1);
    half_t* Zout = Zh + zoff_f(l);
    for (int vb = bid; vb < ntot; vb += G) {
      if (vb < 256) {
        sq_body(T, T, Tout, vb & 7, (vb >> 3) & 7, vb >> 6, s0, s1, s2, s3);
      } else {
        int b = vb - 256;
        sweep_body(Zin, 1024L, T, Zin + 512, 1024L, Zout, (half_t*)0, 512L,
                   1, 0, 0, Mup, b >> 3, b & 7, s0, s1, s2);
      }
    }
    gsync();
  }

  // ---- down-sweep l=11..1 ----
  for (int l = 11; l >= 1; --l) {
    int M = 1 << (11 - l);
    const half_t* Xup = (l == 11) ? x0h : Xph + xoff_f(l + 1);
    half_t* Ch = Xph + xoff_f(l);
    const float* Sm = Sp + (size_t)(l - 1) * MSZ;
    const half_t* Dz = Zh + zoff_f(l);
    int nb = ((M + 63) / 64) * 8;
    for (int vb = bid; vb < nb; vb += G)
      sweep_body(Xup, 512L, Sm, Dz, 1024L, Ch, (half_t*)0, 512L,
                 2, 1, 1, M, vb >> 3, vb & 7, s0, s1, s2);
    gsync();
  }

  // ---- l=0 phase: xtail (cols 512..543) + down-sweep l=0 (cols 0..511) ----
  // Sp dead now (down l=1 consumed Sp[0]); Xcat overlay live. Disjoint columns.
  // M = 2048 (X_1 rows -> odd rows of 4096-row Xcat). R8/R9 BUG was M=4096
  // here: overflow rows aliased the Xcl overlay -> NaN.
  {
    for (int e = bid * 256 + tid; e < 4096 * 32; e += G * 256) {
      int c = e >> 5, j = e & 31;
      float v = (j < 16) ? u[c * 16 + j] : 0.f;
      size_t o = (size_t)c * KPAD + 512 + j;
      half_t h, l; split1r(v, h, l);
      Xch[o] = h; Xcl[o] = l;
    }
    const half_t* Xup = Xph + xoff_f(1);
    for (int vb = bid; vb < 256; vb += G)
      sweep_body(Xup, 512L, Vp + 15 * MSZ, Zh + zoff_f(0), 1024L, Xch, Xcl,
                 (long)KPAD, 2, 1, 1, 2048, vb >> 3, vb & 7, s0, s1, s2);
  }
}

// ---------------- fallback multi-launch kernels (R3/R7, proven) --------------

__global__ void init_kernel(float4* __restrict__ zp, const float* __restrict__ Ab,
                            float* __restrict__ V0, const float* __restrict__ x0,
                            half_t* __restrict__ xh) {
  int bid = blockIdx.x, tid = threadIdx.x;
  if (bid < 6656) {
    zp[bid * 256 + tid] = make_float4(0.f, 0.f, 0.f, 0.f);
  } else if (bid < 7680) {
    int i = (bid - 6656) * 256 + tid;
    V0[i] = Ab[i];
  } else {
    xh[tid] = (half_t)x0[tid];
    xh[tid + 256] = (half_t)x0[tid + 256];
  }
}

__global__ void kbuild_kernel(const float* __restrict__ V, const float* __restrict__ b,
                              float* __restrict__ K) {
  int gw = blockIdx.x * 4 + (threadIdx.x >> 6);
  int lane = threadIdx.x & 63;
  int t = gw >> 9, n = gw & 511;
  if (t == 0) { if (lane == 0) K[n] = b[n]; return; }
  const float* row = V + (size_t)(t - 1) * MSZ + (size_t)n * 512;
  float acc = 0.f;
#pragma unroll
  for (int m = 0; m < 512; m += 64) acc += row[m + lane] * b[m + lane];
#pragma unroll
  for (int s = 32; s; s >>= 1) acc += __shfl_down(acc, s, 64);
  if (lane == 0) K[t * 512 + n] = acc;
}

__global__ void wcat_fill_kernel(const float* __restrict__ V, const float* __restrict__ K,
                                 half_t* __restrict__ Wh, half_t* __restrict__ Wl) {
  int un = blockIdx.x * 256 + threadIdx.x;     // 8192*68 units
  if (un >= 8192 * 68) return;
  int row = un / 68, kb = un - row * 68;
  int i = row >> 9, n = row & 511;
  f16x8 hv, lv;
  if (kb < 64) {
    const float* vp = V + (size_t)i * MSZ + (size_t)n * 512 + kb * 8;
    float4 v0 = *(const float4*)vp, v1 = *(const float4*)(vp + 4);
    float vv[8] = {v0.x, v0.y, v0.z, v0.w, v1.x, v1.y, v1.z, v1.w};
#pragma unroll
    for (int j = 0; j < 8; ++j) { half_t h, l; split1r(vv[j], h, l); hv[j] = h; lv[j] = l; }
  } else {
#pragma unroll
    for (int j = 0; j < 8; ++j) {
      int k = kb * 8 + j;
      float v = 0.f;
      if (k < 528) { int jj = k - 512; if (jj <= i) v = K[(i - jj) * 512 + n]; }
      half_t h, l; split1r(v, h, l); hv[j] = h; lv[j] = l;
    }
  }
  size_t o = (size_t)row * KPAD + kb * 8;
  *(f16x8*)(Wh + o) = hv;
  *(f16x8*)(Wl + o) = lv;
}

__global__ void leaf_kernel(const float* __restrict__ u, const float* __restrict__ K,
                            half_t* __restrict__ Z) {
  __shared__ float us[16];
  int c = blockIdx.x, n = threadIdx.x;
  if (n < 16) us[n] = u[c * 16 + n];
  __syncthreads();
  float acc = 0.f;
#pragma unroll
  for (int j = 0; j < 16; ++j) acc += K[(15 - j) * 512 + n] * us[j];
  Z[(size_t)c * 512 + n] = (half_t)acc;
}

__global__ void xtail_kernel(const float* __restrict__ u,
                             half_t* __restrict__ Xh, half_t* __restrict__ Xl) {
  int idx = blockIdx.x * 256 + threadIdx.x;
  int c = idx >> 5, j = idx & 31;
  float v = (j < 16) ? u[c * 16 + j] : 0.f;
  size_t o = (size_t)c * KPAD + 512 + j;
  half_t h, l; split1r(v, h, l);
  Xh[o] = h; Xl[o] = l;
}

__global__ __launch_bounds__(256)
void gemm_nn512(const float* __restrict__ A, long sA,
                const float* __restrict__ B, long sB,
                float* __restrict__ C, long sC) {
  __shared__ __align__(16) half_t s0[64 * 32], s1[64 * 32], s2[64 * 32], s3[64 * 32];
  int bz = blockIdx.z, bb = bz >> 2, sl = bz & 3;
  sq_body(A + (size_t)bb * sA, B + (size_t)bb * sB, C + (size_t)bb * sC,
          blockIdx.x, blockIdx.y, sl, s0, s1, s2, s3);
}

__global__ __launch_bounds__(256)
void gemm_nt_sweep(const half_t* __restrict__ A, long ldA,
                   const float* __restrict__ BT,
                   const half_t* __restrict__ D, long ldD,
                   half_t* __restrict__ Ch, half_t* __restrict__ Cl,
                   long ldC, int rScale, int rOff, int doCopy, int M) {
  __shared__ __align__(16) half_t s0[64 * 32], s1[64 * 32], s2[64 * 32];
  sweep_body(A, ldA, BT, D, ldD, Ch, Cl, ldC, rScale, rOff, doCopy, M,
             blockIdx.x, blockIdx.y, s0, s1, s2);
}

__global__ __launch_bounds__(256)
void fused_up(const float* __restrict__ T, float* __restrict__ Tout,
              const half_t* __restrict__ Zin, half_t* __restrict__ Zout, int M) {
  __shared__ __align__(16) half_t s0[64 * 32], s1[64 * 32], s2[64 * 32], s3[64 * 32];
  int bid = blockIdx.x;
  if (bid < 256) {
    sq_body(T, T, Tout, bid & 7, (bid >> 3) & 7, bid >> 6, s0, s1, s2, s3);
  } else {
    int b = bid - 256;
    sweep_body(Zin, 1024L, T, Zin + 512, 1024L, Zout, (half_t*)0, 512L,
               1, 0, 0, M, b >> 3, b & 7, s0, s1, s2);
  }
}

// -------- main GEMM: 4096 x 8192 x 544 --------------------------------------
__device__ inline void load_lds16(const half_t* g, half_t* l) {
  __builtin_amdgcn_global_load_lds(
      (const __attribute__((address_space(1))) uint32_t*)g,
      (__attribute__((address_space(3))) uint32_t*)l, 16, 0, 0);
}

// 256x256 tile, BK=32 (17 steps), 8 waves (2Mx4N), wave tile 128x64.
// LDS: 2 buffers x 4 streams x 256x32 f16 = 128 KiB, dbuf. 3 phases per
// K-step; vmcnt drained once per step. Residual split -> single fp32 acc.
// Unchanged from R6 (113us, MfmaUtil 39%).
__global__ __launch_bounds__(512, 2)
void gemm_main(const half_t* __restrict__ Ah, const half_t* __restrict__ Al,
               const half_t* __restrict__ Bh, const half_t* __restrict__ Bl,
               float* __restrict__ C) {
  __shared__ __align__(16) half_t sm[2 * 4 * 8192];   // 128 KiB
  int bid = blockIdx.x;
  int xcd = bid & 7, loc = bid >> 3;                  // loc 0..63
  int mt = (xcd & 1) * 8 + (loc >> 3);                // 0..15
  int nt = (xcd >> 1) * 8 + (loc & 7);                // 0..31
  int m0 = mt * 256, n0 = nt * 256;
  int tid = threadIdx.x, wave = tid >> 6, lane = tid & 63;
  int wm = (wave & 1) * 128, wn = (wave >> 1) * 64;
  int mm = lane & 15, kseg = lane >> 4;
  f32x4 acc[8][4];
#pragma unroll
  for (int f = 0; f < 8; ++f)
#pragma unroll
    for (int g = 0; g < 4; ++g) acc[f][g] = (f32x4){0.f, 0.f, 0.f, 0.f};

  const size_t ga0 = (size_t)(m0 + wave * 16 + mm) * KPAD + kseg * 8;
  const size_t gb0 = (size_t)(n0 + wave * 16 + mm) * KPAD + kseg * 8;
  const size_t qstep = (size_t)128 * KPAD;            // q=1: +128 rows

  auto stage = [&](int nb, int kt, int q) {
    size_t go = (size_t)kt * 32 + (size_t)q * qstep;
    half_t* d = sm + (size_t)nb * 32768 + (size_t)(wave + 8 * q) * 512;
    load_lds16(Ah + ga0 + go, d);
    load_lds16(Al + ga0 + go, d + 8192);
    load_lds16(Bh + gb0 + go, d + 16384);
    load_lds16(Bl + gb0 + go, d + 24576);
  };

  stage(0, 0, 0);
  stage(0, 0, 1);
  asm volatile("s_waitcnt vmcnt(0)" ::: "memory");
  __builtin_amdgcn_s_barrier();

  const int lread = lane * 8;
  const int arow = (wm >> 4);                          // 0 or 8
  const int brow = (wn >> 4);                          // 0,4,8,12
  for (int kt = 0; kt < 17; ++kt) {
    const int cur = kt & 1;
    const half_t* SA_h = sm + cur * 32768;
    const half_t* SA_l = SA_h + 8192;
    const half_t* SB_h = SA_h + 16384;
    const half_t* SB_l = SA_h + 24576;
    const bool pre = kt < 16;
    f16x8 ah[4], al[4], bh0[2], bl0[2], bh1[2], bl1[2];

    // ---- phase A: quadrant (0,0); stage q0 for next step ----
#pragma unroll
    for (int i = 0; i < 4; ++i) {
      ah[i] = *(const f16x8*)(SA_h + (arow + i) * 512 + lread);
      al[i] = *(const f16x8*)(SA_l + (arow + i) * 512 + lread);
    }
#pragma unroll
    for (int j = 0; j < 2; ++j) {
      bh0[j] = *(const f16x8*)(SB_h + (brow + j) * 512 + lread);
      bl0[j] = *(const f16x8*)(SB_l + (brow + j) * 512 + lread);
    }
    if (pre) stage(cur ^ 1, kt + 1, 0);
    __builtin_amdgcn_s_barrier();
    asm volatile("s_waitcnt lgkmcnt(0)" ::: "memory");
    __builtin_amdgcn_sched_barrier(0);
    __builtin_amdgcn_s_setprio(1);
#pragma unroll
    for (int i = 0; i < 4; ++i)
#pragma unroll
      for (int j = 0; j < 2; ++j) {
        acc[i][j] = __builtin_amdgcn_mfma_f32_16x16x32_f16(ah[i], bh0[j], acc[i][j], 0, 0, 0);
        acc[i][j] = __builtin_amdgcn_mfma_f32_16x16x32_f16(ah[i], bl0[j], acc[i][j], 0, 0, 0);
        acc[i][j] = __builtin_amdgcn_mfma_f32_16x16x32_f16(al[i], bh0[j], acc[i][j], 0, 0, 0);
      }
    __builtin_amdgcn_s_setprio(0);
    __builtin_amdgcn_s_barrier();

    // ---- phase B: quadrant (0,1); reuse a, load b1; stage q1 ----
#pragma unroll
    for (int j = 0; j < 2; ++j) {
      bh1[j] = *(const f16x8*)(SB_h + (brow + 2 + j) * 512 + lread);
      bl1[j] = *(const f16x8*)(SB_l + (brow + 2 + j) * 512 + lread);
    }
    if (pre) stage(cur ^ 1, kt + 1, 1);
    __builtin_amdgcn_s_barrier();
    asm volatile("s_waitcnt lgkmcnt(0)" ::: "memory");
    __builtin_amdgcn_sched_barrier(0);
    __builtin_amdgcn_s_setprio(1);
#pragma unroll
    for (int i = 0; i < 4; ++i)
#pragma unroll
      for (int j = 0; j < 2; ++j) {
        acc[i][2 + j] = __builtin_amdgcn_mfma_f32_16x16x32_f16(ah[i], bh1[j], acc[i][2 + j], 0, 0, 0);
        acc[i][2 + j] = __builtin_amdgcn_mfma_f32_16x16x32_f16(ah[i], bl1[j], acc[i][2 + j], 0, 0, 0);
        acc[i][2 + j] = __builtin_amdgcn_mfma_f32_16x16x32_f16(al[i], bh1[j], acc[i][2 + j], 0, 0, 0);
      }
    __builtin_amdgcn_s_setprio(0);
    __builtin_amdgcn_s_barrier();

    // ---- phase C: quadrants (1,1)+(1,0); load a rows 4..7, reuse b1/b0 ----
#pragma unroll
    for (int i = 0; i < 4; ++i) {
      ah[i] = *(const f16x8*)(SA_h + (arow + 4 + i) * 512 + lread);
      al[i] = *(const f16x8*)(SA_l + (arow + 4 + i) * 512 + lread);
    }
    __builtin_amdgcn_s_barrier();
    asm volatile("s_waitcnt lgkmcnt(0)" ::: "memory");
    __builtin_amdgcn_sched_barrier(0);
    __builtin_amdgcn_s_setprio(1);
#pragma unroll
    for (int i = 0; i < 4; ++i)
#pragma unroll
      for (int j = 0; j < 2; ++j) {
        acc[4 + i][2 + j] = __builtin_amdgcn_mfma_f32_16x16x32_f16(ah[i], bh1[j], acc[4 + i][2 + j], 0, 0, 0);
        acc[4 + i][2 + j] = __builtin_amdgcn_mfma_f32_16x16x32_f16(ah[i], bl1[j], acc[4 + i][2 + j], 0, 0, 0);
        acc[4 + i][2 + j] = __builtin_amdgcn_mfma_f32_16x16x32_f16(al[i], bh1[j], acc[4 + i][2 + j], 0, 0, 0);
      }
#pragma unroll
    for (int i = 0; i < 4; ++i)
#pragma unroll
      for (int j = 0; j < 2; ++j) {
        acc[4 + i][j] = __builtin_amdgcn_mfma_f32_16x16x32_f16(ah[i], bh0[j], acc[4 + i][j], 0, 0, 0);
        acc[4 + i][j] = __builtin_amdgcn_mfma_f32_16x16x32_f16(ah[i], bl0[j], acc[4 + i][j], 0, 0, 0);
        acc[4 + i][j] = __builtin_amdgcn_mfma_f32_16x16x32_f16(al[i], bh0[j], acc[4 + i][j], 0, 0, 0);
      }
    __builtin_amdgcn_s_setprio(0);
    asm volatile("s_waitcnt vmcnt(0)" ::: "memory");   // next step's buffer ready
    __builtin_amdgcn_s_barrier();
  }

  int ml = lane & 15, quad = lane >> 4;
#pragma unroll
  for (int f = 0; f < 8; ++f)
#pragma unroll
    for (int g = 0; g < 4; ++g) {
      int gm = m0 + wm + f * 16 + quad * 4;
      int gn = n0 + wn + g * 16 + ml;
      float* o = C + (size_t)gm * 8192 + gn;
#pragma unroll
      for (int rr = 0; rr < 4; ++rr)
        o[(size_t)rr * 8192] = acc[f][g][rr];
    }
}

// ---------------- host orchestration ----------------

extern "C" void kernel_launch(void* const* d_in, const int* in_sizes, int n_in,
                              void* d_out, int out_size, void* d_ws, size_t ws_size,
                              hipStream_t stream) {
  (void)in_sizes; (void)n_in; (void)out_size; (void)ws_size;
  const float* u  = (const float*)d_in[0];   // 65536
  const float* Ab = (const float*)d_in[1];   // 512x512
  const float* Bb = (const float*)d_in[2];   // 512
  const float* x0 = (const float*)d_in[3];   // 512
  float* out = (float*)d_out;                // 65536x512 fp32

  char* base = (char*)d_ws;
  size_t off = 0;
  auto carve = [&](size_t bytes) -> char* {
    char* p = base + off;
    off = (off + bytes + 255) & ~(size_t)255;
    return p;
  };
  float*  Vp  = (float*)carve(16 * MSZ * 4);             // Ab^1..Ab^16 fp32
  float*  Sp  = (float*)carve(11 * MSZ * 4);             // Ab^{16*2^l}, l=1..11
  float*  Kb  = (float*)carve((size_t)16 * 512 * 4);
  half_t* Wh  = (half_t*)carve((size_t)8192 * KPAD * 2);
  half_t* Wl  = (half_t*)carve((size_t)8192 * KPAD * 2);
  half_t* x0h = (half_t*)carve(512 * 2);
  // Overlays (phase-ordered dead-region reuse):
  size_t zoff[13]; zoff[0] = 0;
  for (int l = 0; l < 12; ++l) zoff[l + 1] = zoff[l] + (size_t)(4096 >> l) * 512;
  size_t xoff[13]; xoff[1] = 0;
  for (int l = 1; l < 12; ++l) xoff[l + 1] = xoff[l] + (size_t)(4096 >> l) * 512;
  half_t* Zh  = (half_t*)Vp;                       // Z pool overlays V[0..8]
  half_t* Xph = (half_t*)((char*)Vp + ((zoff[12] * 2 + 255) & ~(size_t)255));
  half_t* Xch = (half_t*)Sp;                       // Xcat overlays Sp
  half_t* Xcl = (half_t*)((char*)Sp + (((size_t)4096 * KPAD * 2 + 255) & ~(size_t)255));

  // ---- try the cooperative mega-kernel (gated + checked) ----
  bool coop_done = false;
  {
    int dev = 0;
    (void)hipGetDevice(&dev);
    int coopAttr = 0;
    (void)hipDeviceGetAttribute(&coopAttr, hipDeviceAttributeCooperativeLaunch, dev);
    int ncu = 0;
    (void)hipDeviceGetAttribute(&ncu, hipDeviceAttributeMultiprocessorCount, dev);
    int maxb = 0;
    (void)hipOccupancyMaxActiveBlocksPerMultiprocessor(&maxb, (const void*)chain_kernel, 256, 0);
    long cap = (long)maxb * (long)ncu;
    int G = cap < 256 ? (int)cap : 256;
    if (coopAttr && G >= 64) {
      void* kargs[] = {(void*)&u, (void*)&Ab, (void*)&Bb, (void*)&x0,
                       (void*)&Vp, (void*)&Sp, (void*)&Kb, (void*)&Wh, (void*)&Wl,
                       (void*)&x0h, (void*)&Zh, (void*)&Xph, (void*)&Xch, (void*)&Xcl};
      hipError_t ce = hipLaunchCooperativeKernel((const void*)chain_kernel,
                                                 dim3(G), dim3(256), kargs, 0, stream);
      coop_done = (ce == hipSuccess);
    }
  }

  if (!coop_done) {
    // ---- fallback: proven R3/R7 multi-launch chain ----
    hipLaunchKernelGGL(init_kernel, dim3(7681), dim3(256), 0, stream,
                       (float4*)(Vp + MSZ), Ab, Vp, x0, x0h);
    for (int s = 1; s <= 8; s <<= 1) {
      hipLaunchKernelGGL(gemm_nn512, dim3(8, 8, 4 * s), dim3(256), 0, stream,
                         Vp, (long)MSZ,
                         Vp + (size_t)(s - 1) * MSZ, 0L,
                         Vp + (size_t)s * MSZ, (long)MSZ);
    }
    hipLaunchKernelGGL(kbuild_kernel, dim3(2048), dim3(256), 0, stream, Vp, Bb, Kb);
    hipLaunchKernelGGL(wcat_fill_kernel, dim3(2176), dim3(256), 0, stream,
                       Vp, Kb, Wh, Wl);
    hipLaunchKernelGGL(leaf_kernel, dim3(4096), dim3(512), 0, stream, u, Kb, Zh);
    for (int l = 1; l <= 11; ++l) {
      const float* T = (l == 1) ? Vp + 15 * MSZ : Sp + (size_t)(l - 2) * MSZ;
      float* Tout = Sp + (size_t)(l - 1) * MSZ;
      int Mup = 1 << (12 - l);
      int nswp = ((Mup + 63) / 64) * 8;
      hipLaunchKernelGGL(fused_up, dim3(256 + nswp), dim3(256), 0, stream,
                         T, Tout, Zh + zoff[l - 1], Zh + zoff[l], Mup);
    }
    auto Smat = [&](int l) -> const float* {
      return (l == 0) ? (Vp + 15 * MSZ) : (Sp + (size_t)(l - 1) * MSZ);
    };
    for (int l = 11; l >= 0; --l) {
      int M = 1 << (11 - l);
      const half_t* Xup = (l == 11) ? x0h : Xph + xoff[l + 1];
      half_t* Ch = (l == 0) ? Xch : Xph + xoff[l];
      half_t* Cl = (l == 0) ? Xcl : (half_t*)0;
      long ldC = (l == 0) ? (long)KPAD : 512L;
      if (l == 0) {
        hipLaunchKernelGGL(xtail_kernel, dim3(512), dim3(256), 0, stream, u, Xch, Xcl);
      }
      hipLaunchKernelGGL(gemm_nt_sweep, dim3((unsigned)((M + 63) / 64), 8), dim3(256), 0, stream,
                         Xup, 512L, Smat(l),
                         Zh + zoff[l], 1024L,
                         Ch, Cl, ldC, 2, 1, 1, M);
    }
  }

  // Main GEMM: all 65536x512 outputs, fp32 store. 512 blocks x 512 threads.
  hipLaunchKernelGGL(gemm_main, dim3(512), dim3(512), 0, stream, Xch, Xcl, Wh, Wl, out);
}

// Round 7
// 642.169 us; speedup vs baseline: 3.2874x; 3.2874x over previous
//
#include <hip/hip_runtime.h>
#include <cstdint>
#include <cstddef>

// HiPPO x_{k+1} = Ab x_k + b u_k, f[k]=x_{k+1}, L=65536, N=512.
// Chunked scan (C=16, G=4096): one big GEMM F(4096x8192)=Xcat(4096x544)@Wcat,
// chunk states via Blelloch sweep with on-device matrix powers.
// Numerics: split-f16 (Ootomo), fp32 accumulate -> ~22-bit mantissa.
// R11: coop grid.sync measured ~50us/sync on MI355X (R6: 30 syncs -> 1890us
// chain, MfmaUtil 0.6%) -> abandoned. Back to R3 multi-launch + ALGEBRAIC
// launch fusion: down-sweep level-PAIRS. X_l from X_{l+2} directly:
//   X_l[4j]   = X_{l+2}[j]
//   X_l[4j+1] = S_l X_{l+2}[j] + Z_l[4j]
//   X_l[4j+2] = S_{l+1} X_{l+2}[j] + Z_{l+1}[2j]
//   X_l[4j+3] = (S_l S_{l+1}) X_{l+2}[j] + (S_l Z_{l+1}[2j] + Z_l[4j+2])
// Three sweep GEMMs/pair (same FLOPs as 2 levels), P/YZ operators precomputed
// (prep launch + per-pair P-rotation). 12 down + xtail -> prep + 6 pairs.
// Dispatches 33 -> 27. gemm_main (113us, MfmaUtil 39%) unchanged.
// Workspace ~49.3 MB (stay under 53 MB).

typedef _Float16 half_t;
typedef _Float16 f16x8 __attribute__((ext_vector_type(8)));
typedef float f32x4 __attribute__((ext_vector_type(4)));

static constexpr int KPAD = 544;               // 512 + 16 u-taps + 16 pad
static constexpr size_t MSZ = (size_t)512 * 512;
static constexpr float INV2048 = 1.f / 2048.f;

__device__ inline void split1(float v, half_t& h, half_t& l) {
  h = (half_t)v;
  l = (half_t)((v - (float)h) * 2048.f);
}
// residual split: l is the true residual; gemm_main accumulates cross terms
// directly into one fp32 accumulator.
__device__ inline void split1r(float v, half_t& h, half_t& l) {
  h = (half_t)v;
  l = (half_t)(v - (float)h);
}

// -------- chain GEMM body: C (+)= A(512x512 fp32) @ B(512x512 fp32) ----------
// split-on-the-fly, fragment-native LDS, 64x64 tile, K-range [k0off, k0off+NKT*32).
// NKT/ATOM compile-time: split-K callers <4,true> (atomicAdd, pre-zeroed C);
// full-K callers <16,false> (direct store, no zero needed).
template <int NKT, bool ATOM>
__device__ __forceinline__ void sq_body(
    const float* __restrict__ A, const float* __restrict__ B, float* __restrict__ C,
    int bx, int by, int k0off,
    half_t* __restrict__ Ash, half_t* __restrict__ Asl,
    half_t* __restrict__ Bsh, half_t* __restrict__ Bsl) {
  int m0 = bx * 64, n0 = by * 64;
  int tid = threadIdx.x, wave = tid >> 6, lane = tid & 63;
  int wm = (wave & 1) * 32, wn = (wave >> 1) * 32;
  f32x4 acc[2][2], accc[2][2];
#pragma unroll
  for (int i = 0; i < 2; ++i)
#pragma unroll
    for (int j = 0; j < 2; ++j) {
      acc[i][j] = (f32x4){0.f, 0.f, 0.f, 0.f};
      accc[i][j] = (f32x4){0.f, 0.f, 0.f, 0.f};
    }
  int rb = tid >> 6, mm = tid & 15, kseg = (tid >> 4) & 3;
  const float* ar = A + (size_t)(m0 + rb * 16 + mm) * 512 + k0off + kseg * 8;
  const float* bc = B + (size_t)(k0off + kseg * 8) * 512 + n0 + rb * 16 + mm;
  float4 a0 = *(const float4*)ar, a1 = *(const float4*)(ar + 4);
  float bv[8];
#pragma unroll
  for (int j = 0; j < 8; ++j) bv[j] = bc[(size_t)j * 512];
#pragma unroll
  for (int kt = 0; kt < NKT; ++kt) {
    {
      float aa[8] = {a0.x, a0.y, a0.z, a0.w, a1.x, a1.y, a1.z, a1.w};
      f16x8 hv, lv;
#pragma unroll
      for (int j = 0; j < 8; ++j) { half_t h, l; split1(aa[j], h, l); hv[j] = h; lv[j] = l; }
      *(f16x8*)(Ash + tid * 8) = hv;
      *(f16x8*)(Asl + tid * 8) = lv;
#pragma unroll
      for (int j = 0; j < 8; ++j) { half_t h, l; split1(bv[j], h, l); hv[j] = h; lv[j] = l; }
      *(f16x8*)(Bsh + tid * 8) = hv;
      *(f16x8*)(Bsl + tid * 8) = lv;
    }
    __syncthreads();
    if (kt < NKT - 1) {   // prefetch kt+1 under this kt's ds_read+mfma
      a0 = *(const float4*)(ar + (kt + 1) * 32);
      a1 = *(const float4*)(ar + (kt + 1) * 32 + 4);
#pragma unroll
      for (int j = 0; j < 8; ++j) bv[j] = bc[(size_t)((kt + 1) * 32 + j) * 512];
    }
    f16x8 afh[2], afl[2], bfh[2], bfl[2];
#pragma unroll
    for (int i = 0; i < 2; ++i) {
      int ra = (wm >> 4) + i, rbn = (wn >> 4) + i;
      afh[i] = *(const f16x8*)(Ash + ra * 512 + lane * 8);
      afl[i] = *(const f16x8*)(Asl + ra * 512 + lane * 8);
      bfh[i] = *(const f16x8*)(Bsh + rbn * 512 + lane * 8);
      bfl[i] = *(const f16x8*)(Bsl + rbn * 512 + lane * 8);
    }
#pragma unroll
    for (int i = 0; i < 2; ++i)
#pragma unroll
      for (int j = 0; j < 2; ++j) {
        acc[i][j] = __builtin_amdgcn_mfma_f32_16x16x32_f16(afh[i], bfh[j], acc[i][j], 0, 0, 0);
        accc[i][j] = __builtin_amdgcn_mfma_f32_16x16x32_f16(afh[i], bfl[j], accc[i][j], 0, 0, 0);
        accc[i][j] = __builtin_amdgcn_mfma_f32_16x16x32_f16(afl[i], bfh[j], accc[i][j], 0, 0, 0);
      }
    __syncthreads();
  }
  int ml = lane & 15, quad = lane >> 4;
  for (int i = 0; i < 2; ++i)
    for (int j = 0; j < 2; ++j)
      for (int rr = 0; rr < 4; ++rr) {
        int gm = m0 + wm + i * 16 + quad * 4 + rr;
        int gn = n0 + wn + j * 16 + ml;
        float v = acc[i][j][rr] + accc[i][j][rr] * INV2048;
        if (ATOM) atomicAdd(&C[(size_t)gm * 512 + gn], v);
        else C[(size_t)gm * 512 + gn] = v;
      }
}

// -------- sweep GEMM body: C(Mx512) = A(Mx512 f16) @ S^T + D; S fp32 ---------
// Depth-2 register prefetch; fused even-row copy writes out[rScale*arow].
__device__ __forceinline__ void sweep_body(
    const half_t* __restrict__ A, long ldA, const float* __restrict__ BT,
    const half_t* __restrict__ D, long ldD,
    half_t* __restrict__ Ch, half_t* __restrict__ Cl, long ldC,
    int rScale, int rOff, int doCopy, int M, int bx, int by,
    half_t* __restrict__ Ash, half_t* __restrict__ Bsh, half_t* __restrict__ Bsl) {
  int m0 = bx * 64, n0 = by * 64;
  int tid = threadIdx.x, wave = tid >> 6, lane = tid & 63;
  int wm = (wave & 1) * 32, wn = (wave >> 1) * 32;
  f32x4 acc[2][2], accc[2][2];
#pragma unroll
  for (int i = 0; i < 2; ++i)
#pragma unroll
    for (int j = 0; j < 2; ++j) {
      acc[i][j] = (f32x4){0.f, 0.f, 0.f, 0.f};
      accc[i][j] = (f32x4){0.f, 0.f, 0.f, 0.f};
    }
  int rb = tid >> 6, mm = tid & 15, kseg = (tid >> 4) & 3;
  int arow = m0 + rb * 16 + mm;
  const half_t* ap = A + (size_t)arow * ldA + kseg * 8;
  const float* bp = BT + (size_t)(n0 + rb * 16 + mm) * 512 + kseg * 8;
  f16x8 av = (f16x8){0, 0, 0, 0, 0, 0, 0, 0};
  if (arow < M) av = *(const f16x8*)ap;
  float4 bv0 = *(const float4*)bp;
  float4 bv1 = *(const float4*)(bp + 4);
#pragma unroll
  for (int kt = 0; kt < 16; ++kt) {
    int k0 = kt * 32;
    *(f16x8*)(Ash + tid * 8) = av;
    // fused copy: out[rScale*arow, k0+kseg*8 ..] = A row values
    if (doCopy && k0 >= n0 && k0 < n0 + 64 && arow < M) {
      size_t co = (size_t)rScale * arow * ldC + k0 + kseg * 8;
      *(f16x8*)(Ch + co) = av;
      if (Cl) *(f16x8*)(Cl + co) = (f16x8){0, 0, 0, 0, 0, 0, 0, 0};
    }
    {
      float bb[8] = {bv0.x, bv0.y, bv0.z, bv0.w, bv1.x, bv1.y, bv1.z, bv1.w};
      f16x8 hv, lv;
#pragma unroll
      for (int j = 0; j < 8; ++j) { half_t h, l; split1(bb[j], h, l); hv[j] = h; lv[j] = l; }
      *(f16x8*)(Bsh + tid * 8) = hv;
      *(f16x8*)(Bsl + tid * 8) = lv;
    }
    __syncthreads();
    if (kt < 15) {  // prefetch kt+1 under this kt's ds_read+mfma
      if (arow < M) av = *(const f16x8*)(ap + (kt + 1) * 32);
      bv0 = *(const float4*)(bp + (kt + 1) * 32);
      bv1 = *(const float4*)(bp + (kt + 1) * 32 + 4);
    }
    f16x8 af[2], bfh[2], bfl[2];
#pragma unroll
    for (int i = 0; i < 2; ++i) {
      af[i] = *(const f16x8*)(Ash + ((wm >> 4) + i) * 512 + lane * 8);
      bfh[i] = *(const f16x8*)(Bsh + ((wn >> 4) + i) * 512 + lane * 8);
      bfl[i] = *(const f16x8*)(Bsl + ((wn >> 4) + i) * 512 + lane * 8);
    }
#pragma unroll
    for (int i = 0; i < 2; ++i)
#pragma unroll
      for (int j = 0; j < 2; ++j) {
        acc[i][j] = __builtin_amdgcn_mfma_f32_16x16x32_f16(af[i], bfh[j], acc[i][j], 0, 0, 0);
        accc[i][j] = __builtin_amdgcn_mfma_f32_16x16x32_f16(af[i], bfl[j], accc[i][j], 0, 0, 0);
      }
    __syncthreads();
  }
  int ml = lane & 15, quad = lane >> 4;
  for (int i = 0; i < 2; ++i)
    for (int j = 0; j < 2; ++j)
      for (int rr = 0; rr < 4; ++rr) {
        int gm = m0 + wm + i * 16 + quad * 4 + rr;
        int gn = n0 + wn + j * 16 + ml;
        if (gm >= M) continue;
        float v = acc[i][j][rr] + accc[i][j][rr] * INV2048;
        if (D) v += (float)D[(size_t)gm * ldD + gn];
        size_t co = ((size_t)gm * rScale + rOff) * ldC + gn;
        if (Cl) { half_t h, l; split1r(v, h, l); Ch[co] = h; Cl[co] = l; }
        else Ch[co] = (half_t)v;
      }
}

// closed forms (elements): zoff[l] = 2^22 - 2^(22-l); xoff[l] = 2^21 - 2^(22-l)
__device__ __forceinline__ size_t zoff_f(int l) {
  return ((size_t)1 << 22) - ((size_t)1 << (22 - l));
}

// ---------------- small kernels ----------------

__global__ void init_kernel(float4* __restrict__ zp, const float* __restrict__ Ab,
                            float* __restrict__ V0, const float* __restrict__ x0,
                            half_t* __restrict__ xh) {
  int bid = blockIdx.x, tid = threadIdx.x;
  if (bid < 6656) {                       // zero V[1..15]+Sp = 26*MSZ fp32
    zp[bid * 256 + tid] = make_float4(0.f, 0.f, 0.f, 0.f);
  } else if (bid < 7680) {                // copy Ab -> V0
    int i = (bid - 6656) * 256 + tid;
    V0[i] = Ab[i];
  } else {
    xh[tid] = (half_t)x0[tid];
    xh[tid + 256] = (half_t)x0[tid + 256];
  }
}

__global__ void kbuild_kernel(const float* __restrict__ V, const float* __restrict__ b,
                              float* __restrict__ K) {
  int gw = blockIdx.x * 4 + (threadIdx.x >> 6);
  int lane = threadIdx.x & 63;
  int t = gw >> 9, n = gw & 511;
  if (t == 0) { if (lane == 0) K[n] = b[n]; return; }
  const float* row = V + (size_t)(t - 1) * MSZ + (size_t)n * 512;
  float acc = 0.f;
#pragma unroll
  for (int m = 0; m < 512; m += 64) acc += row[m + lane] * b[m + lane];
#pragma unroll
  for (int s = 32; s; s >>= 1) acc += __shfl_down(acc, s, 64);
  if (lane == 0) K[t * 512 + n] = acc;
}

__global__ void wcat_fill_kernel(const float* __restrict__ V, const float* __restrict__ K,
                                 half_t* __restrict__ Wh, half_t* __restrict__ Wl) {
  int un = blockIdx.x * 256 + threadIdx.x;     // 8192*68 units of 8 cols
  if (un >= 8192 * 68) return;
  int row = un / 68, kb = un - row * 68;
  int i = row >> 9, n = row & 511;
  f16x8 hv, lv;
  if (kb < 64) {
    const float* vp = V + (size_t)i * MSZ + (size_t)n * 512 + kb * 8;
    float4 v0 = *(const float4*)vp, v1 = *(const float4*)(vp + 4);
    float vv[8] = {v0.x, v0.y, v0.z, v0.w, v1.x, v1.y, v1.z, v1.w};
#pragma unroll
    for (int j = 0; j < 8; ++j) { half_t h, l; split1r(vv[j], h, l); hv[j] = h; lv[j] = l; }
  } else {
#pragma unroll
    for (int j = 0; j < 8; ++j) {
      int k = kb * 8 + j;
      float v = 0.f;
      if (k < 528) { int jj = k - 512; if (jj <= i) v = K[(i - jj) * 512 + n]; }
      half_t h, l; split1r(v, h, l); hv[j] = h; lv[j] = l;
    }
  }
  size_t o = (size_t)row * KPAD + kb * 8;
  *(f16x8*)(Wh + o) = hv;
  *(f16x8*)(Wl + o) = lv;
}

__global__ void leaf_kernel(const float* __restrict__ u, const float* __restrict__ K,
                            half_t* __restrict__ Z) {
  __shared__ float us[16];
  int c = blockIdx.x, n = threadIdx.x;
  if (n < 16) us[n] = u[c * 16 + n];
  __syncthreads();
  float acc = 0.f;
#pragma unroll
  for (int j = 0; j < 16; ++j) acc += K[(15 - j) * 512 + n] * us[j];
  Z[(size_t)c * 512 + n] = (half_t)acc;
}

// -------- V-chain / squaring launches --------
__global__ __launch_bounds__(256)
void gemm_nn512(const float* __restrict__ A, long sA,
                const float* __restrict__ B, long sB,
                float* __restrict__ C, long sC) {
  __shared__ __align__(16) half_t s0[64 * 32], s1[64 * 32], s2[64 * 32], s3[64 * 32];
  int bz = blockIdx.z, bb = bz >> 2, sl = bz & 3;
  sq_body<4, true>(A + (size_t)bb * sA, B + (size_t)bb * sB, C + (size_t)bb * sC,
                   blockIdx.x, blockIdx.y, sl * 128, s0, s1, s2, s3);
}

// fused: squaring T_l = T_{l-1}^2 (blocks 0..255, split-K=4) + up-sweep l-1
__global__ __launch_bounds__(256)
void fused_up(const float* __restrict__ T, float* __restrict__ Tout,
              const half_t* __restrict__ Zin, half_t* __restrict__ Zout, int M) {
  __shared__ __align__(16) half_t s0[64 * 32], s1[64 * 32], s2[64 * 32], s3[64 * 32];
  int bid = blockIdx.x;
  if (bid < 256) {
    sq_body<4, true>(T, T, Tout, bid & 7, (bid >> 3) & 7, (bid >> 6) * 128, s0, s1, s2, s3);
  } else {
    int b = bid - 256;
    sweep_body(Zin, 1024L, T, Zin + 512, 1024L, Zout, (half_t*)0, 512L,
               1, 0, 0, M, b >> 3, b & 7, s0, s1, s2);
  }
}

// -------- prep: P_10 = S_10 @ S_11 (full-K, direct store) + all YZ + S1 copy -
// YZ_l[j] = S_l Z_{l+1}[2j] + Z_l[4j+2], for l in {10,8,6,4,2,0}.
__global__ __launch_bounds__(256)
void prep_kernel(const float* __restrict__ Vp, const float* __restrict__ Sp,
                 const half_t* __restrict__ Zh, half_t* __restrict__ YZp,
                 float* __restrict__ P10, float* __restrict__ S1c) {
  __shared__ __align__(16) half_t s0[64 * 32], s1[64 * 32], s2[64 * 32], s3[64 * 32];
  int bid = blockIdx.x, tid = threadIdx.x;
  if (bid < 64) {   // P_10 = S_10 @ S_11
    sq_body<16, false>(Sp + (size_t)9 * MSZ, Sp + (size_t)10 * MSZ, P10,
                       bid & 7, bid >> 3, 0, s0, s1, s2, s3);
    return;
  }
  int yb = bid - 64;
  const int yzr[6] = {0, 1, 5, 21, 85, 341};   // row offsets in YZp
#pragma unroll
  for (int t = 0; t < 6; ++t) {
    int l = 10 - 2 * t;
    int M0 = 1 << (2 * t);
    int nb = ((M0 + 63) >> 6) * 8;
    if (yb < nb) {
      const float* Sl = (l == 0) ? Vp + 15 * MSZ : Sp + (size_t)(l - 1) * MSZ;
      sweep_body(Zh + zoff_f(l + 1), 1024L, Sl,
                 Zh + zoff_f(l) + 1024, 2048L,
                 YZp + (size_t)yzr[t] * 512, (half_t*)0, 512L,
                 1, 0, 0, M0, yb >> 3, yb & 7, s0, s1, s2);
      return;
    }
    yb -= nb;
  }
  // remaining 256 blocks: copy S_1 (Sp[0], 1 MSZ fp32) -> S1c (Xcat overlays Sp
  // at pair-5, which still needs S_1)
  ((float4*)S1c)[(size_t)yb * 256 + tid] = ((const float4*)Sp)[(size_t)yb * 256 + tid];
}

// -------- down pair: X_l from X_{l+2} via 3 sweep roles + copy ---------------
// role 0: rows 4j+1 = S_l x + Z_l[4j]        (also copies rows 4j)
// role 1: rows 4j+2 = S_{l+1} x + Z_{l+1}[2j]
// role 2: rows 4j+3 = P_l x + YZ_l[j]
// + optional next-pair P GEMM (64 blocks) + optional xtail (pair 5).
__global__ __launch_bounds__(256)
void down_pair(const half_t* __restrict__ Xin, int M0,
               const float* __restrict__ Sl, const float* __restrict__ Sl1,
               const float* __restrict__ Pl,
               const half_t* __restrict__ Zl, const half_t* __restrict__ Zl1,
               const half_t* __restrict__ YZ,
               half_t* __restrict__ Ch, half_t* __restrict__ Cl, long ldC,
               const float* __restrict__ Pna, const float* __restrict__ Pnb,
               float* __restrict__ Pnout, const float* __restrict__ uu) {
  __shared__ __align__(16) half_t s0[64 * 32], s1[64 * 32], s2[64 * 32], s3[64 * 32];
  int bid = blockIdx.x, tid = threadIdx.x;
  int nrole = ((M0 + 63) >> 6) * 8;
  if (bid < 3 * nrole) {
    int r = bid / nrole, b = bid - r * nrole;
    const float* BT = (r == 0) ? Sl : (r == 1) ? Sl1 : Pl;
    const half_t* D = (r == 0) ? Zl : (r == 1) ? Zl1 : YZ;
    long ldD = (r == 0) ? 2048L : (r == 1) ? 1024L : 512L;
    sweep_body(Xin, 512L, BT, D, ldD, Ch, Cl, ldC,
               4, r + 1, (r == 0) ? 1 : 0, M0, b >> 3, b & 7, s0, s1, s2);
    return;
  }
  int rest = bid - 3 * nrole;
  if (Pnout) {   // compute next pair's P = S_{l-2} @ S_{l-1} (full-K direct)
    sq_body<16, false>(Pna, Pnb, Pnout, rest & 7, rest >> 3, 0, s0, s1, s2, s3);
    return;
  }
  // xtail (pair 5 only): Xcat cols [512,544)
  int idx = rest * 256 + tid;
  int c = idx >> 5, j = idx & 31;
  float v = (j < 16) ? uu[c * 16 + j] : 0.f;
  size_t o = (size_t)c * KPAD + 512 + j;
  half_t h, l; split1r(v, h, l);
  Ch[o] = h; Cl[o] = l;
}

// -------- main GEMM: 4096 x 8192 x 544 --------------------------------------
__device__ inline void load_lds16(const half_t* g, half_t* l) {
  __builtin_amdgcn_global_load_lds(
      (const __attribute__((address_space(1))) uint32_t*)g,
      (__attribute__((address_space(3))) uint32_t*)l, 16, 0, 0);
}

// 256x256 tile, BK=32 (17 steps), 8 waves (2Mx4N), wave tile 128x64.
// LDS 128 KiB dbuf; 3 phases/K-step; vmcnt drained once per step; residual
// split -> single fp32 acc. Unchanged (113us, MfmaUtil 39%).
__global__ __launch_bounds__(512, 2)
void gemm_main(const half_t* __restrict__ Ah, const half_t* __restrict__ Al,
               const half_t* __restrict__ Bh, const half_t* __restrict__ Bl,
               float* __restrict__ C) {
  __shared__ __align__(16) half_t sm[2 * 4 * 8192];   // 128 KiB
  int bid = blockIdx.x;
  int xcd = bid & 7, loc = bid >> 3;                  // loc 0..63
  int mt = (xcd & 1) * 8 + (loc >> 3);                // 0..15
  int nt = (xcd >> 1) * 8 + (loc & 7);                // 0..31
  int m0 = mt * 256, n0 = nt * 256;
  int tid = threadIdx.x, wave = tid >> 6, lane = tid & 63;
  int wm = (wave & 1) * 128, wn = (wave >> 1) * 64;
  int mm = lane & 15, kseg = lane >> 4;
  f32x4 acc[8][4];
#pragma unroll
  for (int f = 0; f < 8; ++f)
#pragma unroll
    for (int g = 0; g < 4; ++g) acc[f][g] = (f32x4){0.f, 0.f, 0.f, 0.f};

  const size_t ga0 = (size_t)(m0 + wave * 16 + mm) * KPAD + kseg * 8;
  const size_t gb0 = (size_t)(n0 + wave * 16 + mm) * KPAD + kseg * 8;
  const size_t qstep = (size_t)128 * KPAD;            // q=1: +128 rows

  auto stage = [&](int nb, int kt, int q) {
    size_t go = (size_t)kt * 32 + (size_t)q * qstep;
    half_t* d = sm + (size_t)nb * 32768 + (size_t)(wave + 8 * q) * 512;
    load_lds16(Ah + ga0 + go, d);
    load_lds16(Al + ga0 + go, d + 8192);
    load_lds16(Bh + gb0 + go, d + 16384);
    load_lds16(Bl + gb0 + go, d + 24576);
  };

  stage(0, 0, 0);
  stage(0, 0, 1);
  asm volatile("s_waitcnt vmcnt(0)" ::: "memory");
  __builtin_amdgcn_s_barrier();

  const int lread = lane * 8;
  const int arow = (wm >> 4);                          // 0 or 8
  const int brow = (wn >> 4);                          // 0,4,8,12
  for (int kt = 0; kt < 17; ++kt) {
    const int cur = kt & 1;
    const half_t* SA_h = sm + cur * 32768;
    const half_t* SA_l = SA_h + 8192;
    const half_t* SB_h = SA_h + 16384;
    const half_t* SB_l = SA_h + 24576;
    const bool pre = kt < 16;
    f16x8 ah[4], al[4], bh0[2], bl0[2], bh1[2], bl1[2];

    // ---- phase A: quadrant (0,0); stage q0 for next step ----
#pragma unroll
    for (int i = 0; i < 4; ++i) {
      ah[i] = *(const f16x8*)(SA_h + (arow + i) * 512 + lread);
      al[i] = *(const f16x8*)(SA_l + (arow + i) * 512 + lread);
    }
#pragma unroll
    for (int j = 0; j < 2; ++j) {
      bh0[j] = *(const f16x8*)(SB_h + (brow + j) * 512 + lread);
      bl0[j] = *(const f16x8*)(SB_l + (brow + j) * 512 + lread);
    }
    if (pre) stage(cur ^ 1, kt + 1, 0);
    __builtin_amdgcn_s_barrier();
    asm volatile("s_waitcnt lgkmcnt(0)" ::: "memory");
    __builtin_amdgcn_sched_barrier(0);
    __builtin_amdgcn_s_setprio(1);
#pragma unroll
    for (int i = 0; i < 4; ++i)
#pragma unroll
      for (int j = 0; j < 2; ++j) {
        acc[i][j] = __builtin_amdgcn_mfma_f32_16x16x32_f16(ah[i], bh0[j], acc[i][j], 0, 0, 0);
        acc[i][j] = __builtin_amdgcn_mfma_f32_16x16x32_f16(ah[i], bl0[j], acc[i][j], 0, 0, 0);
        acc[i][j] = __builtin_amdgcn_mfma_f32_16x16x32_f16(al[i], bh0[j], acc[i][j], 0, 0, 0);
      }
    __builtin_amdgcn_s_setprio(0);
    __builtin_amdgcn_s_barrier();

    // ---- phase B: quadrant (0,1); reuse a, load b1; stage q1 ----
#pragma unroll
    for (int j = 0; j < 2; ++j) {
      bh1[j] = *(const f16x8*)(SB_h + (brow + 2 + j) * 512 + lread);
      bl1[j] = *(const f16x8*)(SB_l + (brow + 2 + j) * 512 + lread);
    }
    if (pre) stage(cur ^ 1, kt + 1, 1);
    __builtin_amdgcn_s_barrier();
    asm volatile("s_waitcnt lgkmcnt(0)" ::: "memory");
    __builtin_amdgcn_sched_barrier(0);
    __builtin_amdgcn_s_setprio(1);
#pragma unroll
    for (int i = 0; i < 4; ++i)
#pragma unroll
      for (int j = 0; j < 2; ++j) {
        acc[i][2 + j] = __builtin_amdgcn_mfma_f32_16x16x32_f16(ah[i], bh1[j], acc[i][2 + j], 0, 0, 0);
        acc[i][2 + j] = __builtin_amdgcn_mfma_f32_16x16x32_f16(ah[i], bl1[j], acc[i][2 + j], 0, 0, 0);
        acc[i][2 + j] = __builtin_amdgcn_mfma_f32_16x16x32_f16(al[i], bh1[j], acc[i][2 + j], 0, 0, 0);
      }
    __builtin_amdgcn_s_setprio(0);
    __builtin_amdgcn_s_barrier();

    // ---- phase C: quadrants (1,1)+(1,0); load a rows 4..7, reuse b1/b0 ----
#pragma unroll
    for (int i = 0; i < 4; ++i) {
      ah[i] = *(const f16x8*)(SA_h + (arow + 4 + i) * 512 + lread);
      al[i] = *(const f16x8*)(SA_l + (arow + 4 + i) * 512 + lread);
    }
    __builtin_amdgcn_s_barrier();
    asm volatile("s_waitcnt lgkmcnt(0)" ::: "memory");
    __builtin_amdgcn_sched_barrier(0);
    __builtin_amdgcn_s_setprio(1);
#pragma unroll
    for (int i = 0; i < 4; ++i)
#pragma unroll
      for (int j = 0; j < 2; ++j) {
        acc[4 + i][2 + j] = __builtin_amdgcn_mfma_f32_16x16x32_f16(ah[i], bh1[j], acc[4 + i][2 + j], 0, 0, 0);
        acc[4 + i][2 + j] = __builtin_amdgcn_mfma_f32_16x16x32_f16(ah[i], bl1[j], acc[4 + i][2 + j], 0, 0, 0);
        acc[4 + i][2 + j] = __builtin_amdgcn_mfma_f32_16x16x32_f16(al[i], bh1[j], acc[4 + i][2 + j], 0, 0, 0);
      }
#pragma unroll
    for (int i = 0; i < 4; ++i)
#pragma unroll
      for (int j = 0; j < 2; ++j) {
        acc[4 + i][j] = __builtin_amdgcn_mfma_f32_16x16x32_f16(ah[i], bh0[j], acc[4 + i][j], 0, 0, 0);
        acc[4 + i][j] = __builtin_amdgcn_mfma_f32_16x16x32_f16(ah[i], bl0[j], acc[4 + i][j], 0, 0, 0);
        acc[4 + i][j] = __builtin_amdgcn_mfma_f32_16x16x32_f16(al[i], bh0[j], acc[4 + i][j], 0, 0, 0);
      }
    __builtin_amdgcn_s_setprio(0);
    asm volatile("s_waitcnt vmcnt(0)" ::: "memory");   // next step's buffer ready
    __builtin_amdgcn_s_barrier();
  }

  int ml = lane & 15, quad = lane >> 4;
#pragma unroll
  for (int f = 0; f < 8; ++f)
#pragma unroll
    for (int g = 0; g < 4; ++g) {
      int gm = m0 + wm + f * 16 + quad * 4;
      int gn = n0 + wn + g * 16 + ml;
      float* o = C + (size_t)gm * 8192 + gn;
#pragma unroll
      for (int rr = 0; rr < 4; ++rr)
        o[(size_t)rr * 8192] = acc[f][g][rr];
    }
}

// ---------------- host orchestration ----------------

extern "C" void kernel_launch(void* const* d_in, const int* in_sizes, int n_in,
                              void* d_out, int out_size, void* d_ws, size_t ws_size,
                              hipStream_t stream) {
  (void)in_sizes; (void)n_in; (void)out_size; (void)ws_size;
  const float* u  = (const float*)d_in[0];   // 65536
  const float* Ab = (const float*)d_in[1];   // 512x512
  const float* Bb = (const float*)d_in[2];   // 512
  const float* x0 = (const float*)d_in[3];   // 512
  float* out = (float*)d_out;                // 65536x512 fp32

  char* base = (char*)d_ws;
  size_t off = 0;
  auto carve = [&](size_t bytes) -> char* {
    char* p = base + off;
    off = (off + bytes + 255) & ~(size_t)255;
    return p;
  };
  float*  Vp  = (float*)carve(16 * MSZ * 4);             // Ab^1..Ab^16 fp32
  float*  Sp  = (float*)carve(11 * MSZ * 4);             // Ab^{16*2^l}, l=1..11
  float*  Kb  = (float*)carve((size_t)16 * 512 * 4);
  half_t* Wh  = (half_t*)carve((size_t)8192 * KPAD * 2);
  half_t* Wl  = (half_t*)carve((size_t)8192 * KPAD * 2);
  half_t* x0h = (half_t*)carve(512 * 2);
  float*  Pp  = (float*)carve(3 * MSZ * 4);              // P rotation (2) + S1 copy
  float*  Pb0 = Pp;
  float*  Pb1 = Pp + MSZ;
  float*  S1c = Pp + 2 * MSZ;

  // Overlays (phase-ordered dead-region reuse):
  size_t zoff[13]; zoff[0] = 0;
  for (int l = 0; l < 12; ++l) zoff[l + 1] = zoff[l] + (size_t)(4096 >> l) * 512;
  size_t xoff[13]; xoff[1] = 0;
  for (int l = 1; l < 12; ++l) xoff[l + 1] = xoff[l] + (size_t)(4096 >> l) * 512;
  half_t* Zh  = (half_t*)Vp;                        // Z pool overlays V[0..8]
  size_t xphOff = (zoff[12] * 2 + 255) & ~(size_t)255;
  half_t* Xph = (half_t*)((char*)Vp + xphOff);      // X pool (even levels)
  // YZ pool in the free Vp gap after Xph, before V15 (= S_0, still live):
  // [12578816, 15728640): need 1365 rows * 1KB = 1397760 B. Verified fit.
  half_t* YZp = (half_t*)((char*)Vp + xphOff + ((xoff[12] * 2 + 255) & ~(size_t)255));
  half_t* Xch = (half_t*)Sp;                        // Xcat overlays Sp (pair 5)
  half_t* Xcl = (half_t*)((char*)Sp + (((size_t)4096 * KPAD * 2 + 255) & ~(size_t)255));

  // init: zero V[1..15]+Sp (26*MSZ, atomic targets) + copy Ab + cast x0
  hipLaunchKernelGGL(init_kernel, dim3(7681), dim3(256), 0, stream,
                     (float4*)(Vp + MSZ), Ab, Vp, x0, x0h);

  // V-chain by doubling: V_{t+s} = V_t @ V_s, t=1..s; s=1,2,4,8 (split-K=4)
  for (int s = 1; s <= 8; s <<= 1) {
    hipLaunchKernelGGL(gemm_nn512, dim3(8, 8, 4 * s), dim3(256), 0, stream,
                       Vp, (long)MSZ,
                       Vp + (size_t)(s - 1) * MSZ, 0L,
                       Vp + (size_t)s * MSZ, (long)MSZ);
  }
  hipLaunchKernelGGL(kbuild_kernel, dim3(2048), dim3(256), 0, stream, Vp, Bb, Kb);
  hipLaunchKernelGGL(wcat_fill_kernel, dim3(2176), dim3(256), 0, stream, Vp, Kb, Wh, Wl);
  // From here V[0..14] dead -> Z overlay valid (leaf writes Zh over V0/V1).
  hipLaunchKernelGGL(leaf_kernel, dim3(4096), dim3(512), 0, stream, u, Kb, Zh);

  auto Smat = [&](int l) -> const float* {
    return (l == 0) ? (Vp + 15 * MSZ) : (Sp + (size_t)(l - 1) * MSZ);
  };

  // up: FL_l = squaring S_l = S_{l-1}^2 + up-sweep level l-1 (l=1..11)
  for (int l = 1; l <= 11; ++l) {
    const float* T = Smat(l - 1);
    float* Tout = Sp + (size_t)(l - 1) * MSZ;
    int Mup = 1 << (12 - l);
    int nswp = ((Mup + 63) / 64) * 8;
    hipLaunchKernelGGL(fused_up, dim3(256 + nswp), dim3(256), 0, stream,
                       T, Tout, Zh + zoff[l - 1], Zh + zoff[l], Mup);
  }

  // prep: P_10 + all YZ levels + S1 copy (grid 64 + 192 + 256)
  hipLaunchKernelGGL(prep_kernel, dim3(512), dim3(256), 0, stream,
                     Vp, Sp, Zh, YZp, Pb0, S1c);

  // down pairs i=0..5: levels (11-2i, 10-2i); pair i also computes next P.
  const int yzrow[6] = {0, 1, 5, 21, 85, 341};
  for (int i = 0; i < 6; ++i) {
    int l = 10 - 2 * i;
    int M0 = 1 << (2 * i);
    const float* Sl  = Smat(l);
    const float* Sl1 = (i == 5) ? S1c : Smat(l + 1);
    const float* Pl  = (i & 1) ? Pb1 : Pb0;
    const float* Pna = (i < 5) ? Smat(l - 2) : (const float*)0;
    const float* Pnb = (i < 5) ? Smat(l - 1) : (const float*)0;
    float* Pnout     = (i < 5) ? ((i & 1) ? Pb0 : Pb1) : (float*)0;
    const half_t* Xin = (i == 0) ? x0h : Xph + xoff[l + 2];
    half_t* Ch = (i == 5) ? Xch : Xph + xoff[l];
    half_t* Cl = (i == 5) ? Xcl : (half_t*)0;
    long ldC = (i == 5) ? (long)KPAD : 512L;
    const float* uu = (i == 5) ? u : (const float*)0;
    int nrole = ((M0 + 63) / 64) * 8;
    int grid = 3 * nrole + (i < 5 ? 64 : 0) + (i == 5 ? 512 : 0);
    hipLaunchKernelGGL(down_pair, dim3(grid), dim3(256), 0, stream,
                       Xin, M0, Sl, Sl1, Pl,
                       Zh + zoff[l], Zh + zoff[l + 1],
                       YZp + (size_t)yzrow[i] * 512,
                       Ch, Cl, ldC, Pna, Pnb, Pnout, uu);
  }

  // Main GEMM: all 65536x512 outputs, fp32 store. 512 blocks x 512 threads.
  hipLaunchKernelGGL(gemm_main, dim3(512), dim3(512), 0, stream, Xch, Xcl, Wh, Wl, out);
}